// Round 1
// baseline (173.491 us; speedup 1.0000x reference)
//
#include <hip/hip_runtime.h>

#define DD 128

// ---------------------------------------------------------------------------
// prep: build CSR row offsets from sorted dst, and transpose W (WT[k][j]=W[j][k])
// ---------------------------------------------------------------------------
__global__ void prep_kernel(const int* __restrict__ dst, const float* __restrict__ W,
                            int* __restrict__ row_start, float* __restrict__ WT,
                            int nEdges, int nNodes) {
  int e = blockIdx.x * 256 + threadIdx.x;
  if (e <= nEdges) {
    if (e == 0) {
      int d0 = dst[0];
      for (int n = 0; n <= d0; ++n) row_start[n] = 0;
    } else if (e == nEdges) {
      for (int n = dst[nEdges - 1] + 1; n <= nNodes; ++n) row_start[n] = nEdges;
    } else {
      int d = dst[e], dp = dst[e - 1];
      for (int n = dp + 1; n <= d; ++n) row_start[n] = e;
    }
  }
  if (e < DD * DD) {
    int k = e >> 7, j = e & 127;
    WT[e] = W[j * DD + k];
  }
}

// ---------------------------------------------------------------------------
// hidden = x @ W^T + b.  Block: 256 threads, 32 nodes.
// LDS: half of WT (64x128 = 32KB) staged twice + x tile (32x128 = 16KB) = 48KB.
// Thread: 4 nodes x 4 cols, k unrolled by 4 -> 64 FMA per 8 ds_read_b128.
// ---------------------------------------------------------------------------
__global__ __launch_bounds__(256, 3) void hidden_gemm(
    const float* __restrict__ x, const float* __restrict__ WT,
    const float* __restrict__ bias, float* __restrict__ hidden) {
  __shared__ float sW[64 * DD];   // 32KB: one K-half of WT
  __shared__ float sX[32 * DD];   // 16KB: node tile of x
  int t = threadIdx.x;
  int n0 = blockIdx.x * 32;

  // stage x tile (coalesced float4)
  const float4* x4 = (const float4*)(x + (size_t)n0 * DD);
  float4* sX4 = (float4*)sX;
#pragma unroll
  for (int i = 0; i < 4; ++i) sX4[t + i * 256] = x4[t + i * 256];

  int g = t >> 5, li = t & 31;
  int c = li * 4;    // col base
  int nb = g * 4;    // node base within tile
  float acc[4][4] = {{0.f}};

  for (int half = 0; half < 2; ++half) {
    __syncthreads();
    // stage one K-half of WT: 64*128 floats = 2048 float4
    const float4* WT4 = (const float4*)(WT + half * 64 * DD);
    float4* sW4 = (float4*)sW;
#pragma unroll
    for (int i = 0; i < 8; ++i) sW4[t + i * 256] = WT4[t + i * 256];
    __syncthreads();

    for (int k = 0; k < 64; k += 4) {
      float wv[4][4];
#pragma unroll
      for (int kk = 0; kk < 4; ++kk)
        *(float4*)wv[kk] = *(const float4*)&sW[(k + kk) * DD + c];
#pragma unroll
      for (int m = 0; m < 4; ++m) {
        float4 xv = *(const float4*)&sX[(nb + m) * DD + half * 64 + k];
#pragma unroll
        for (int cc = 0; cc < 4; ++cc)
          acc[m][cc] += xv.x * wv[0][cc] + xv.y * wv[1][cc] +
                        xv.z * wv[2][cc] + xv.w * wv[3][cc];
      }
    }
  }

  float4 bb = *(const float4*)&bias[c];
  float ba[4] = {bb.x, bb.y, bb.z, bb.w};
#pragma unroll
  for (int m = 0; m < 4; ++m) {
    float4 o;
    o.x = acc[m][0] + ba[0];
    o.y = acc[m][1] + ba[1];
    o.z = acc[m][2] + ba[2];
    o.w = acc[m][3] + ba[3];
    *(float4*)&hidden[(size_t)(n0 + nb + m) * DD + c] = o;
  }
}

// ---------------------------------------------------------------------------
// support = relu(segment_sum(edge_w * hidden[src], dst)) -> written to d_out.
// One wave (64 lanes) per node; lane covers 2 cols (float2 -> 512B/row gather).
// Edge range from precomputed CSR offsets; scalarized via readfirstlane.
// ---------------------------------------------------------------------------
__global__ __launch_bounds__(256, 4) void scatter_relu(
    const float* __restrict__ hidden, const int* __restrict__ src,
    const float* __restrict__ ew, const int* __restrict__ row_start,
    float* __restrict__ support) {
  int w = threadIdx.x >> 6;
  int l = threadIdx.x & 63;
  int n = blockIdx.x * 4 + w;
  int b = __builtin_amdgcn_readfirstlane(row_start[n]);
  int e = __builtin_amdgcn_readfirstlane(row_start[n + 1]);
  int col = l * 2;
  float a0x = 0.f, a0y = 0.f, a1x = 0.f, a1y = 0.f;
  float a2x = 0.f, a2y = 0.f, a3x = 0.f, a3y = 0.f;
  int idx = b;
  for (; idx + 4 <= e; idx += 4) {
    int s0 = src[idx], s1 = src[idx + 1], s2 = src[idx + 2], s3 = src[idx + 3];
    float w0 = ew[idx], w1 = ew[idx + 1], w2 = ew[idx + 2], w3 = ew[idx + 3];
    float2 h0 = *(const float2*)&hidden[s0 * DD + col];
    float2 h1 = *(const float2*)&hidden[s1 * DD + col];
    float2 h2 = *(const float2*)&hidden[s2 * DD + col];
    float2 h3 = *(const float2*)&hidden[s3 * DD + col];
    a0x += w0 * h0.x; a0y += w0 * h0.y;
    a1x += w1 * h1.x; a1y += w1 * h1.y;
    a2x += w2 * h2.x; a2y += w2 * h2.y;
    a3x += w3 * h3.x; a3y += w3 * h3.y;
  }
  for (; idx < e; ++idx) {
    int s = src[idx];
    float wgt = ew[idx];
    float2 h = *(const float2*)&hidden[s * DD + col];
    a0x += wgt * h.x; a0y += wgt * h.y;
  }
  float2 r;
  r.x = fmaxf(a0x + a1x + a2x + a3x, 0.f);
  r.y = fmaxf(a0y + a1y + a2y + a3y, 0.f);
  *(float2*)&support[n * DD + col] = r;
}

// ---------------------------------------------------------------------------
// gate = sigmoid(x @ KG + bg); out = gate*support + (1-gate)*x.
// Same structure as hidden_gemm (KG is already [k][j]); support lives in d_out
// and is overwritten in place.
// ---------------------------------------------------------------------------
__global__ __launch_bounds__(256, 3) void gate_combine(
    const float* __restrict__ x, const float* __restrict__ KG,
    const float* __restrict__ bg, float* __restrict__ out) {
  __shared__ float sG[64 * DD];
  __shared__ float sX[32 * DD];
  int t = threadIdx.x;
  int n0 = blockIdx.x * 32;

  const float4* x4 = (const float4*)(x + (size_t)n0 * DD);
  float4* sX4 = (float4*)sX;
#pragma unroll
  for (int i = 0; i < 4; ++i) sX4[t + i * 256] = x4[t + i * 256];

  int g = t >> 5, li = t & 31;
  int c = li * 4;
  int nb = g * 4;
  float acc[4][4] = {{0.f}};

  for (int half = 0; half < 2; ++half) {
    __syncthreads();
    const float4* G4 = (const float4*)(KG + half * 64 * DD);
    float4* sG4 = (float4*)sG;
#pragma unroll
    for (int i = 0; i < 8; ++i) sG4[t + i * 256] = G4[t + i * 256];
    __syncthreads();

    for (int k = 0; k < 64; k += 4) {
      float wv[4][4];
#pragma unroll
      for (int kk = 0; kk < 4; ++kk)
        *(float4*)wv[kk] = *(const float4*)&sG[(k + kk) * DD + c];
#pragma unroll
      for (int m = 0; m < 4; ++m) {
        float4 xv = *(const float4*)&sX[(nb + m) * DD + half * 64 + k];
#pragma unroll
        for (int cc = 0; cc < 4; ++cc)
          acc[m][cc] += xv.x * wv[0][cc] + xv.y * wv[1][cc] +
                        xv.z * wv[2][cc] + xv.w * wv[3][cc];
      }
    }
  }

  float4 bb = *(const float4*)&bg[c];
  float ba[4] = {bb.x, bb.y, bb.z, bb.w};
#pragma unroll
  for (int m = 0; m < 4; ++m) {
    size_t row = (size_t)(n0 + nb + m) * DD + c;
    float4 sv = *(const float4*)&out[row];  // support (relu'd)
    float s[4] = {sv.x, sv.y, sv.z, sv.w};
    float o[4];
#pragma unroll
    for (int cc = 0; cc < 4; ++cc) {
      float z = acc[m][cc] + ba[cc];
      float gt = 1.0f / (1.0f + __expf(-z));
      float xv = sX[(nb + m) * DD + c + cc];
      o[cc] = gt * s[cc] + (1.0f - gt) * xv;
    }
    float4 ov = {o[0], o[1], o[2], o[3]};
    *(float4*)&out[row] = ov;
  }
}

// ---------------------------------------------------------------------------
extern "C" void kernel_launch(void* const* d_in, const int* in_sizes, int n_in,
                              void* d_out, int out_size, void* d_ws, size_t ws_size,
                              hipStream_t stream) {
  const float* x  = (const float*)d_in[0];
  const int*   src = (const int*)d_in[1];
  const int*   dst = (const int*)d_in[2];
  const float* ew = (const float*)d_in[3];
  const float* W  = (const float*)d_in[4];
  const float* b  = (const float*)d_in[5];
  const float* KG = (const float*)d_in[6];
  const float* bg = (const float*)d_in[7];
  float* out = (float*)d_out;

  int N = in_sizes[0] / DD;
  int E = in_sizes[1];

  float* hidden = (float*)d_ws;                        // N*DD floats
  float* WT = hidden + (size_t)N * DD;                 // DD*DD floats
  int* row_start = (int*)(WT + DD * DD);               // N+1 ints

  int prepBlocks = (E + 1 + 255) / 256;
  prep_kernel<<<prepBlocks, 256, 0, stream>>>(dst, W, row_start, WT, E, N);
  hidden_gemm<<<N / 32, 256, 0, stream>>>(x, WT, b, hidden);
  scatter_relu<<<N / 4, 256, 0, stream>>>(hidden, src, ew, row_start, out);
  gate_combine<<<N / 32, 256, 0, stream>>>(x, KG, bg, out);
}

// Round 2
// 93.596 us; speedup vs baseline: 1.8536x; 1.8536x over previous
//
#include <hip/hip_runtime.h>

#define DD 128

typedef __attribute__((ext_vector_type(8))) short bf16x8;
typedef __attribute__((ext_vector_type(4))) float f32x4;

__device__ __forceinline__ unsigned short f2bf(float f) {
  unsigned int u = __float_as_uint(f);
  return (unsigned short)((u + 0x7FFFu + ((u >> 16) & 1u)) >> 16);
}
__device__ __forceinline__ float bf_lo(unsigned int v) {
  return __uint_as_float(v << 16);
}
__device__ __forceinline__ float bf_hi(unsigned int v) {
  return __uint_as_float(v & 0xFFFF0000u);
}

// ---------------------------------------------------------------------------
// prep: CSR row offsets from sorted dst; B = concat(W[j][k], KG^T[j][k]) as bf16.
// B row j<128 -> W[j][k]  (hidden cols);  j>=128 -> KG[k][j-128]  (gate cols).
// ---------------------------------------------------------------------------
__global__ void prep_kernel(const int* __restrict__ dst, const float* __restrict__ W,
                            const float* __restrict__ KG, int* __restrict__ row_start,
                            unsigned short* __restrict__ B, int nEdges, int nNodes) {
  int e = blockIdx.x * 256 + threadIdx.x;
  if (e <= nEdges) {
    if (e == 0) {
      int d0 = dst[0];
      for (int n = 0; n <= d0; ++n) row_start[n] = 0;
    } else if (e == nEdges) {
      for (int n = dst[nEdges - 1] + 1; n <= nNodes; ++n) row_start[n] = nEdges;
    } else {
      int d = dst[e], dp = dst[e - 1];
      for (int n = dp + 1; n <= d; ++n) row_start[n] = e;
    }
  }
  if (e < 2 * DD * DD) {
    int j = e >> 7, k = e & 127;
    float v = (j < DD) ? W[j * DD + k] : KG[k * DD + (j - DD)];
    B[e] = f2bf(v);
  }
}

// ---------------------------------------------------------------------------
// dual_gemm: [hidden | z] = x @ B^T   (M=100k nodes, N=256 cols, K=128), bf16 MFMA.
// Block: 256 thr / 4 waves, tile 64 nodes x 256 cols; wave w owns cols w*64..+63.
// Waves 0,1 -> hidden (+bias, store bf16); waves 2,3 -> gate (sigmoid, store bf16).
// LDS: sX [64][128] bf16 + sB [256][128] bf16, both XOR-swizzled (G4).
// ---------------------------------------------------------------------------
__global__ __launch_bounds__(256, 2) void dual_gemm(
    const float* __restrict__ x, const unsigned short* __restrict__ B,
    const float* __restrict__ bias, const float* __restrict__ bg,
    unsigned short* __restrict__ hb, unsigned short* __restrict__ gw, int N) {
  __shared__ char smem[(16 + 64) * 1024];
  unsigned short* sX = (unsigned short*)smem;             // 16KB
  unsigned short* sB = (unsigned short*)(smem + 16384);   // 64KB
  int t = threadIdx.x;
  int wid = t >> 6, lane = t & 63;
  int M0 = blockIdx.x * 64;

  // ---- stage x tile (f32 -> bf16, swizzled) : 2048 float4
#pragma unroll
  for (int i = 0; i < 8; ++i) {
    int f4 = i * 256 + t;
    int r = f4 >> 5;            // row in tile
    int kk = (f4 & 31) * 4;     // bf16 col
    float4 v;
    if (M0 + r < N) v = ((const float4*)x)[(size_t)(M0 + r) * 32 + (f4 & 31)];
    else            v = make_float4(0.f, 0.f, 0.f, 0.f);
    unsigned int lo = (unsigned int)f2bf(v.x) | ((unsigned int)f2bf(v.y) << 16);
    unsigned int hi = (unsigned int)f2bf(v.z) | ((unsigned int)f2bf(v.w) << 16);
    int off = (r * 256 + kk * 2) ^ ((r & 7) << 4);
    uint2 q = {lo, hi};
    *(uint2*)((char*)sX + off) = q;
  }
  // ---- stage B (already bf16 in ws, swizzled write): 4096 uint4
#pragma unroll
  for (int i = 0; i < 16; ++i) {
    int idx = i * 256 + t;
    int j = idx >> 4;
    int k8 = (idx & 15) * 8;
    uint4 v = ((const uint4*)B)[idx];
    int off = (j * 256 + k8 * 2) ^ ((j & 7) << 4);
    *(uint4*)((char*)sB + off) = v;
  }
  __syncthreads();

  int n0 = wid * 64;
  int lr = lane & 15, lk = (lane >> 4) * 8;
  f32x4 acc[4][4];
#pragma unroll
  for (int m = 0; m < 4; ++m)
#pragma unroll
    for (int nr = 0; nr < 4; ++nr) acc[m][nr] = (f32x4){0.f, 0.f, 0.f, 0.f};

#pragma unroll
  for (int kc = 0; kc < 4; ++kc) {
    int kb = (kc * 32 + lk) * 2;  // byte offset within a row
    bf16x8 a[4], bb[4];
#pragma unroll
    for (int m = 0; m < 4; ++m) {
      int r = m * 16 + lr;
      a[m] = *(const bf16x8*)((const char*)sX + ((r * 256 + kb) ^ ((r & 7) << 4)));
    }
#pragma unroll
    for (int nr = 0; nr < 4; ++nr) {
      int j = n0 + nr * 16 + lr;
      bb[nr] = *(const bf16x8*)((const char*)sB + ((j * 256 + kb) ^ ((j & 7) << 4)));
    }
#pragma unroll
    for (int m = 0; m < 4; ++m)
#pragma unroll
      for (int nr = 0; nr < 4; ++nr)
        acc[m][nr] = __builtin_amdgcn_mfma_f32_16x16x32_bf16(a[m], bb[nr], acc[m][nr], 0, 0, 0);
  }

  // ---- epilogue: C row = m*16 + (lane>>4)*4 + reg, col = n0 + nr*16 + (lane&15)
  bool isGate = (wid >= 2);
  unsigned short* dbuf = isGate ? gw : hb;
  int cb = isGate ? (n0 - 128) : n0;   // col base within the 128-wide buffer
#pragma unroll
  for (int nr = 0; nr < 4; ++nr) {
    int col = cb + nr * 16 + lr;
    float bv = isGate ? bg[col] : bias[col];
#pragma unroll
    for (int m = 0; m < 4; ++m) {
      int row0 = M0 + m * 16 + ((lane >> 4) << 2);
      f32x4 v = acc[m][nr];
#pragma unroll
      for (int reg = 0; reg < 4; ++reg) {
        float z = v[reg] + bv;
        if (isGate) z = 1.0f / (1.0f + __expf(-z));
        if (row0 + reg < N) dbuf[(size_t)(row0 + reg) * DD + col] = f2bf(z);
      }
    }
  }
}

// ---------------------------------------------------------------------------
// scatter_combine: support = relu(segment_sum(ew * hb[src])), then
// out = gate*support + (1-gate)*x.  One wave per node; lane covers 2 cols.
// ---------------------------------------------------------------------------
__global__ __launch_bounds__(256, 4) void scatter_combine(
    const unsigned short* __restrict__ hb, const unsigned short* __restrict__ gw,
    const float* __restrict__ x, const int* __restrict__ src,
    const float* __restrict__ ew, const int* __restrict__ row_start,
    float* __restrict__ out) {
  int w = threadIdx.x >> 6;
  int lane = threadIdx.x & 63;
  int n = blockIdx.x * 4 + w;
  int b = __builtin_amdgcn_readfirstlane(row_start[n]);
  int e = __builtin_amdgcn_readfirstlane(row_start[n + 1]);
  const unsigned int* h32 = (const unsigned int*)hb;

  float a0x = 0.f, a0y = 0.f, a1x = 0.f, a1y = 0.f;
  float a2x = 0.f, a2y = 0.f, a3x = 0.f, a3y = 0.f;
  int i = b;
  for (; i + 4 <= e; i += 4) {
    int s0 = src[i], s1 = src[i + 1], s2 = src[i + 2], s3 = src[i + 3];
    float w0 = ew[i], w1 = ew[i + 1], w2 = ew[i + 2], w3 = ew[i + 3];
    unsigned int v0 = h32[(size_t)s0 * 64 + lane];
    unsigned int v1 = h32[(size_t)s1 * 64 + lane];
    unsigned int v2 = h32[(size_t)s2 * 64 + lane];
    unsigned int v3 = h32[(size_t)s3 * 64 + lane];
    a0x += w0 * bf_lo(v0); a0y += w0 * bf_hi(v0);
    a1x += w1 * bf_lo(v1); a1y += w1 * bf_hi(v1);
    a2x += w2 * bf_lo(v2); a2y += w2 * bf_hi(v2);
    a3x += w3 * bf_lo(v3); a3y += w3 * bf_hi(v3);
  }
  for (; i < e; ++i) {
    int s = src[i];
    float wt = ew[i];
    unsigned int v = h32[(size_t)s * 64 + lane];
    a0x += wt * bf_lo(v); a0y += wt * bf_hi(v);
  }
  float sx = fmaxf(a0x + a1x + a2x + a3x, 0.f);
  float sy = fmaxf(a0y + a1y + a2y + a3y, 0.f);

  unsigned int g2 = ((const unsigned int*)gw)[(size_t)n * 64 + lane];
  float gx = bf_lo(g2), gy = bf_hi(g2);
  float2 xv = *(const float2*)&x[(size_t)n * DD + lane * 2];
  float2 o;
  o.x = gx * sx + (1.f - gx) * xv.x;
  o.y = gy * sy + (1.f - gy) * xv.y;
  *(float2*)&out[(size_t)n * DD + lane * 2] = o;
}

// ---------------------------------------------------------------------------
extern "C" void kernel_launch(void* const* d_in, const int* in_sizes, int n_in,
                              void* d_out, int out_size, void* d_ws, size_t ws_size,
                              hipStream_t stream) {
  const float* x   = (const float*)d_in[0];
  const int*   src = (const int*)d_in[1];
  const int*   dst = (const int*)d_in[2];
  const float* ew  = (const float*)d_in[3];
  const float* W   = (const float*)d_in[4];
  const float* b   = (const float*)d_in[5];
  const float* KG  = (const float*)d_in[6];
  const float* bg  = (const float*)d_in[7];
  float* out = (float*)d_out;

  int N = in_sizes[0] / DD;
  int E = in_sizes[1];

  unsigned short* hb = (unsigned short*)d_ws;              // N*128 bf16
  unsigned short* gw = hb + (size_t)N * DD;                // N*128 bf16
  unsigned short* B  = gw + (size_t)N * DD;                // 256*128 bf16
  int* row_start = (int*)(B + 2 * DD * DD);                // N+1 ints

  int prepBlocks = (E + 1 + 255) / 256;
  prep_kernel<<<prepBlocks, 256, 0, stream>>>(dst, W, KG, row_start, B, E, N);
  dual_gemm<<<(N + 63) / 64, 256, 0, stream>>>(x, B, b, bg, hb, gw, N);
  scatter_combine<<<N / 4, 256, 0, stream>>>(hb, gw, x, src, ew, row_start, out);
}

// Round 3
// 88.391 us; speedup vs baseline: 1.9628x; 1.0589x over previous
//
#include <hip/hip_runtime.h>

#define DD 128

typedef __attribute__((ext_vector_type(8))) short bf16x8;
typedef __attribute__((ext_vector_type(4))) float f32x4;

__device__ __forceinline__ unsigned int cvt_pk_bf16(float lo, float hi) {
  unsigned int r;
  asm("v_cvt_pk_bf16_f32 %0, %1, %2" : "=v"(r) : "v"(lo), "v"(hi));
  return r;
}
__device__ __forceinline__ float bf_lo(unsigned int v) {
  return __uint_as_float(v << 16);
}
__device__ __forceinline__ float bf_hi(unsigned int v) {
  return __uint_as_float(v & 0xFFFF0000u);
}

// ---------------------------------------------------------------------------
// prep: CSR row offsets from sorted dst; B = concat(W[j][k], KG^T[j][k]) as bf16.
// ---------------------------------------------------------------------------
__global__ void prep_kernel(const int* __restrict__ dst, const float* __restrict__ W,
                            const float* __restrict__ KG, int* __restrict__ row_start,
                            unsigned short* __restrict__ B, int nEdges, int nNodes) {
  int e = blockIdx.x * 256 + threadIdx.x;
  if (e <= nEdges) {
    if (e == 0) {
      int d0 = dst[0];
      for (int n = 0; n <= d0; ++n) row_start[n] = 0;
    } else if (e == nEdges) {
      for (int n = dst[nEdges - 1] + 1; n <= nNodes; ++n) row_start[n] = nEdges;
    } else {
      int d = dst[e], dp = dst[e - 1];
      for (int n = dp + 1; n <= d; ++n) row_start[n] = e;
    }
  }
  if (e < 2 * DD * DD) {
    int j = e >> 7, k = e & 127;
    float v = (j < DD) ? W[j * DD + k] : KG[k * DD + (j - DD)];
    B[e] = (unsigned short)cvt_pk_bf16(v, v);
  }
}

// ---------------------------------------------------------------------------
// dual_gemm: [hidden | z] = x @ B^T  (M=100k, N=256, K=128), bf16 MFMA.
// 256 thr / 4 waves; tile 64 nodes; wave w -> cols w*64..+63.
// B fragments preloaded to registers from global (L2-resident, 64 VGPR);
// LDS holds only the x tile (16KB, XOR-swizzled bf16).
// ---------------------------------------------------------------------------
__global__ __launch_bounds__(256, 3) void dual_gemm(
    const float* __restrict__ x, const unsigned short* __restrict__ B,
    const float* __restrict__ bias, const float* __restrict__ bg,
    unsigned short* __restrict__ hb, unsigned short* __restrict__ gw, int N) {
  __shared__ char smem[16 * 1024];
  unsigned short* sX = (unsigned short*)smem;
  int t = threadIdx.x;
  int wid = t >> 6, lane = t & 63;
  int M0 = blockIdx.x * 64;
  int n0 = wid * 64;
  int lr = lane & 15, lk = (lane >> 4) * 8;

  // ---- preload B fragments (issue before staging so latency hides)
  bf16x8 bfr[4][4];  // [kc][nr]
#pragma unroll
  for (int kc = 0; kc < 4; ++kc)
#pragma unroll
    for (int nr = 0; nr < 4; ++nr)
      bfr[kc][nr] = *(const bf16x8*)(B + (size_t)(n0 + nr * 16 + lr) * DD + kc * 32 + lk);

  // ---- stage x tile (f32 -> bf16 via cvt_pk, swizzled): 2048 float4
#pragma unroll
  for (int i = 0; i < 8; ++i) {
    int f4 = i * 256 + t;
    int r = f4 >> 5;
    int kk = (f4 & 31) * 4;
    float4 v;
    if (M0 + r < N) v = ((const float4*)x)[(size_t)(M0 + r) * 32 + (f4 & 31)];
    else            v = make_float4(0.f, 0.f, 0.f, 0.f);
    unsigned int lo = cvt_pk_bf16(v.x, v.y);
    unsigned int hi = cvt_pk_bf16(v.z, v.w);
    int off = (r * 256 + kk * 2) ^ ((r & 7) << 4);
    uint2 q = {lo, hi};
    *(uint2*)((char*)sX + off) = q;
  }
  __syncthreads();

  f32x4 acc[4][4];
#pragma unroll
  for (int m = 0; m < 4; ++m)
#pragma unroll
    for (int nr = 0; nr < 4; ++nr) acc[m][nr] = (f32x4){0.f, 0.f, 0.f, 0.f};

#pragma unroll
  for (int kc = 0; kc < 4; ++kc) {
    int kb = (kc * 32 + lk) * 2;
    bf16x8 a[4];
#pragma unroll
    for (int m = 0; m < 4; ++m) {
      int r = m * 16 + lr;
      a[m] = *(const bf16x8*)((const char*)sX + ((r * 256 + kb) ^ ((r & 7) << 4)));
    }
#pragma unroll
    for (int m = 0; m < 4; ++m)
#pragma unroll
      for (int nr = 0; nr < 4; ++nr)
        acc[m][nr] = __builtin_amdgcn_mfma_f32_16x16x32_bf16(a[m], bfr[kc][nr], acc[m][nr], 0, 0, 0);
  }

  // ---- epilogue
  bool isGate = (wid >= 2);
  unsigned short* dbuf = isGate ? gw : hb;
  int cb = isGate ? (n0 - 128) : n0;
#pragma unroll
  for (int nr = 0; nr < 4; ++nr) {
    int col = cb + nr * 16 + lr;
    float bv = isGate ? bg[col] : bias[col];
#pragma unroll
    for (int m = 0; m < 4; ++m) {
      int row0 = M0 + m * 16 + ((lane >> 4) << 2);
      f32x4 v = acc[m][nr];
#pragma unroll
      for (int reg = 0; reg < 4; ++reg) {
        float z = v[reg] + bv;
        if (isGate) z = 1.0f / (1.0f + __expf(-z));
        if (row0 + reg < N)
          dbuf[(size_t)(row0 + reg) * DD + col] = (unsigned short)cvt_pk_bf16(z, z);
      }
    }
  }
}

// ---------------------------------------------------------------------------
// scatter_combine: support = relu(segment_sum(ew * hb[src])),
// out = gate*support + (1-gate)*x.  One wave per node; lane = 2 cols (u32 row).
// ---------------------------------------------------------------------------
__global__ __launch_bounds__(256, 8) void scatter_combine(
    const unsigned short* __restrict__ hb, const unsigned short* __restrict__ gw,
    const float* __restrict__ x, const int* __restrict__ src,
    const float* __restrict__ ew, const int* __restrict__ row_start,
    float* __restrict__ out) {
  int w = threadIdx.x >> 6;
  int lane = threadIdx.x & 63;
  int n = blockIdx.x * 4 + w;
  int b = __builtin_amdgcn_readfirstlane(row_start[n]);
  int e = __builtin_amdgcn_readfirstlane(row_start[n + 1]);
  const unsigned int* h32 = (const unsigned int*)hb;

  // independent loads issued ahead of the gather loop
  unsigned int g2 = ((const unsigned int*)gw)[(size_t)n * 64 + lane];
  float2 xv = *(const float2*)&x[(size_t)n * DD + lane * 2];

  float a0x = 0.f, a0y = 0.f, a1x = 0.f, a1y = 0.f;
  float a2x = 0.f, a2y = 0.f, a3x = 0.f, a3y = 0.f;
  int i = b;
  for (; i + 4 <= e; i += 4) {
    int s0 = src[i], s1 = src[i + 1], s2 = src[i + 2], s3 = src[i + 3];
    float w0 = ew[i], w1 = ew[i + 1], w2 = ew[i + 2], w3 = ew[i + 3];
    unsigned int v0 = h32[(size_t)s0 * 64 + lane];
    unsigned int v1 = h32[(size_t)s1 * 64 + lane];
    unsigned int v2 = h32[(size_t)s2 * 64 + lane];
    unsigned int v3 = h32[(size_t)s3 * 64 + lane];
    a0x += w0 * bf_lo(v0); a0y += w0 * bf_hi(v0);
    a1x += w1 * bf_lo(v1); a1y += w1 * bf_hi(v1);
    a2x += w2 * bf_lo(v2); a2y += w2 * bf_hi(v2);
    a3x += w3 * bf_lo(v3); a3y += w3 * bf_hi(v3);
  }
  for (; i < e; ++i) {
    int s = src[i];
    float wt = ew[i];
    unsigned int v = h32[(size_t)s * 64 + lane];
    a0x += wt * bf_lo(v); a0y += wt * bf_hi(v);
  }
  float sx = fmaxf(a0x + a1x + a2x + a3x, 0.f);
  float sy = fmaxf(a0y + a1y + a2y + a3y, 0.f);

  float gx = bf_lo(g2), gy = bf_hi(g2);
  float2 o;
  o.x = gx * sx + (1.f - gx) * xv.x;
  o.y = gy * sy + (1.f - gy) * xv.y;
  *(float2*)&out[(size_t)n * DD + lane * 2] = o;
}

// ---------------------------------------------------------------------------
extern "C" void kernel_launch(void* const* d_in, const int* in_sizes, int n_in,
                              void* d_out, int out_size, void* d_ws, size_t ws_size,
                              hipStream_t stream) {
  const float* x   = (const float*)d_in[0];
  const int*   src = (const int*)d_in[1];
  const int*   dst = (const int*)d_in[2];
  const float* ew  = (const float*)d_in[3];
  const float* W   = (const float*)d_in[4];
  const float* b   = (const float*)d_in[5];
  const float* KG  = (const float*)d_in[6];
  const float* bg  = (const float*)d_in[7];
  float* out = (float*)d_out;

  int N = in_sizes[0] / DD;
  int E = in_sizes[1];

  unsigned short* hb = (unsigned short*)d_ws;              // N*128 bf16
  unsigned short* gw = hb + (size_t)N * DD;                // N*128 bf16
  unsigned short* B  = gw + (size_t)N * DD;                // 256*128 bf16
  int* row_start = (int*)(B + 2 * DD * DD);                // N+1 ints

  int prepBlocks = (E + 1 + 255) / 256;
  prep_kernel<<<prepBlocks, 256, 0, stream>>>(dst, W, KG, row_start, B, E, N);
  dual_gemm<<<(N + 63) / 64, 256, 0, stream>>>(x, B, b, bg, hb, gw, N);
  scatter_combine<<<N / 4, 256, 0, stream>>>(hb, gw, x, src, ew, row_start, out);
}